// Round 5
// baseline (43.833 us; speedup 1.0000x reference)
//
#include <hip/hip_runtime.h>
#include <math.h>

#define NQ 4
#define NL 2
#define INF 8
#define OUTF 128
#define K2_BLOCKS 512
#define K2_WAVES (K2_BLOCKS * 4)   // 2048 waves, 8 per CU

typedef float fv4 __attribute__((ext_vector_type(4)));

__device__ __forceinline__ float fast_tanh(float x) {
    float e = __expf(2.0f * x);
    return 1.0f - 2.0f / (e + 1.0f);
}

// ---------------- K1: one thread = one row; z[row][0..3] -> zout ----------
__global__ __launch_bounds__(256) void zcalc_kernel(
    const float* __restrict__ x,       // [B,8]
    const float* __restrict__ W_pre,   // [4,8]
    const float* __restrict__ b_pre,   // [4]
    const float* __restrict__ theta,   // [2,4]
    float* __restrict__ zout,          // [B,4] (workspace)
    int B)
{
    const int row = blockIdx.x * 256 + threadIdx.x;
    if (row >= B) return;

    const float4* xr = reinterpret_cast<const float4*>(x + (size_t)row * INF);
    const float4 xa = xr[0], xb = xr[1];

    // embedding angles
    float ca[NQ], sa[NQ];
    #pragma unroll
    for (int w = 0; w < NQ; ++w) {
        const float* wp = W_pre + w * INF;   // wave-uniform -> scalar loads
        float acc = b_pre[w];
        acc += xa.x * wp[0] + xa.y * wp[1] + xa.z * wp[2] + xa.w * wp[3];
        acc += xb.x * wp[4] + xb.y * wp[5] + xb.z * wp[6] + xb.w * wp[7];
        float alpha = 3.14159265358979323846f * fast_tanh(acc);
        __sincosf(0.5f * alpha, &sa[w], &ca[w]);
    }

    // uniform layer trig
    float ct[NL][NQ], st_[NL][NQ];
    #pragma unroll
    for (int l = 0; l < NL; ++l)
        #pragma unroll
        for (int w = 0; w < NQ; ++w)
            __sincosf(0.5f * theta[l * NQ + w], &st_[l][w], &ct[l][w]);

    // statevector sim; wire w <-> bit mask 8>>w; product-state init
    float st[16];
    #pragma unroll
    for (int i = 0; i < 16; ++i) {
        float v = (i & 8) ? sa[0] : ca[0];
        v *= (i & 4) ? sa[1] : ca[1];
        v *= (i & 2) ? sa[2] : ca[2];
        v *= (i & 1) ? sa[3] : ca[3];
        st[i] = v;
    }

    #pragma unroll
    for (int l = 0; l < NL; ++l) {
        #pragma unroll
        for (int w = 0; w < NQ; ++w) {
            const float c = ct[l][w], s = st_[l][w];
            const int bit = 8 >> w;
            #pragma unroll
            for (int i = 0; i < 16; ++i) {
                if (!(i & bit)) {
                    const int j = i | bit;
                    float a0 = st[i], a1 = st[j];
                    st[i] = c * a0 - s * a1;
                    st[j] = s * a0 + c * a1;
                }
            }
        }
        #pragma unroll
        for (int w = 0; w < NQ - 1; ++w) {
            const int cb = 8 >> w, tb = 8 >> (w + 1);
            #pragma unroll
            for (int i = 0; i < 16; ++i) {
                if ((i & cb) && !(i & tb)) {
                    const int j = i | tb;
                    float t = st[i]; st[i] = st[j]; st[j] = t;
                }
            }
        }
    }

    float p[16];
    #pragma unroll
    for (int i = 0; i < 16; ++i) p[i] = st[i] * st[i];

    float z[NQ];
    #pragma unroll
    for (int w = 0; w < NQ; ++w) {
        const int bit = 8 >> w;
        float zp = 0.f, zm = 0.f;
        #pragma unroll
        for (int i = 0; i < 16; ++i) {
            if (i & bit) zm += p[i]; else zp += p[i];
        }
        z[w] = zp - zm;
    }

    // coalesced 16B/lane store (plain: keep z cached for K2)
    *reinterpret_cast<float4*>(zout + (size_t)row * 4) =
        make_float4(z[0], z[1], z[2], z[3]);
}

// ---------------- K2: fill-like sliding-window expansion ------------------
// Global wave g, iteration i handles row-pair rp = i*K2_WAVES + g, i.e. rows
// 2rp (lanes 0-31) and 2rp+1 (lanes 32-63): one contiguous 1KiB wave-store.
// Device-wide, iteration i writes rows [2i*K2_WAVES, 2(i+1)*K2_WAVES): a
// contiguous 2MB window sliding through out — same address pattern as the
// 6.7 TB/s fill kernel.
__global__ __launch_bounds__(256) void expand_kernel(
    const float* __restrict__ z,       // [B,4] (workspace)
    const float* __restrict__ W_post,  // [128,4]
    const float* __restrict__ b_post,  // [128]
    float* __restrict__ out,           // [B,128]
    int B, int iters)
{
    const int lane  = threadIdx.x & 63;
    const int g     = blockIdx.x * 4 + (threadIdx.x >> 6);
    const int colb  = (lane & 31) * 4;
    const int rhalf = lane >> 5;

    const float4 w0 = *reinterpret_cast<const float4*>(W_post + (colb + 0) * NQ);
    const float4 w1 = *reinterpret_cast<const float4*>(W_post + (colb + 1) * NQ);
    const float4 w2 = *reinterpret_cast<const float4*>(W_post + (colb + 2) * NQ);
    const float4 w3 = *reinterpret_cast<const float4*>(W_post + (colb + 3) * NQ);
    const float4 bp = *reinterpret_cast<const float4*>(b_post + colb);

    // prefetch iter 0's z (broadcast load: 32 lanes share one address)
    int row = 2 * g + rhalf;
    float4 zv = make_float4(0.f, 0.f, 0.f, 0.f);
    if (row < B) zv = *reinterpret_cast<const float4*>(z + (size_t)row * 4);

    for (int i = 0; i < iters; ++i) {
        // prefetch next iteration's z (hides L3 latency under this iter)
        const int rown = 2 * ((i + 1) * K2_WAVES + g) + rhalf;
        float4 zn = make_float4(0.f, 0.f, 0.f, 0.f);
        if ((i + 1 < iters) && (rown < B))
            zn = *reinterpret_cast<const float4*>(z + (size_t)rown * 4);

        if (row < B) {
            fv4 o;
            o.x = fmaf(zv.w, w0.w, fmaf(zv.z, w0.z, fmaf(zv.y, w0.y, fmaf(zv.x, w0.x, bp.x))));
            o.y = fmaf(zv.w, w1.w, fmaf(zv.z, w1.z, fmaf(zv.y, w1.y, fmaf(zv.x, w1.x, bp.y))));
            o.z = fmaf(zv.w, w2.w, fmaf(zv.z, w2.z, fmaf(zv.y, w2.y, fmaf(zv.x, w2.x, bp.z))));
            o.w = fmaf(zv.w, w3.w, fmaf(zv.z, w3.z, fmaf(zv.y, w3.y, fmaf(zv.x, w3.x, bp.w))));
            __builtin_nontemporal_store(
                o, reinterpret_cast<fv4*>(out + (size_t)row * OUTF + colb));
        }
        zv = zn;
        row = rown;
    }
}

extern "C" void kernel_launch(void* const* d_in, const int* in_sizes, int n_in,
                              void* d_out, int out_size, void* d_ws, size_t ws_size,
                              hipStream_t stream) {
    const float* x      = (const float*)d_in[0];
    const float* W_pre  = (const float*)d_in[1];
    const float* b_pre  = (const float*)d_in[2];
    const float* theta  = (const float*)d_in[3];
    const float* W_post = (const float*)d_in[4];
    const float* b_post = (const float*)d_in[5];
    float* out = (float*)d_out;
    float* zbuf = (float*)d_ws;   // B*4 floats

    const int B = in_sizes[0] / INF;

    const int k1_blocks = (B + 255) / 256;
    zcalc_kernel<<<dim3(k1_blocks), dim3(256), 0, stream>>>(
        x, W_pre, b_pre, theta, zbuf, B);

    const int rows_per_sweep = 2 * K2_WAVES;                 // 4096 rows/iter
    const int iters = (B + rows_per_sweep - 1) / rows_per_sweep;
    expand_kernel<<<dim3(K2_BLOCKS), dim3(256), 0, stream>>>(
        zbuf, W_post, b_post, out, B, iters);
}

// Round 6
// 30.820 us; speedup vs baseline: 1.4223x; 1.4223x over previous
//
#include <hip/hip_runtime.h>
#include <math.h>

#define NQ 4
#define NL 2
#define INF 8
#define OUTF 128

typedef float fv4 __attribute__((ext_vector_type(4)));

__device__ __forceinline__ float fast_tanh(float x) {
    float e = __expf(2.0f * x);
    return 1.0f - 2.0f / (e + 1.0f);
}

__global__ __launch_bounds__(256) void tq_kernel(
    const float* __restrict__ x,       // [B,8]
    const float* __restrict__ W_pre,   // [4,8]
    const float* __restrict__ b_pre,   // [4]
    const float* __restrict__ theta,   // [2,4]
    const float* __restrict__ W_post,  // [128,4]
    const float* __restrict__ b_post,  // [128]
    float* __restrict__ out,           // [B,128]
    int B)
{
    const int tid = threadIdx.x;
    const int row = blockIdx.x * 256 + tid;

    __shared__ float zsh[256][4];

    if (row < B) {
        // ---- phase 1: embedding angles ----
        const float4* xr = reinterpret_cast<const float4*>(x + (size_t)row * INF);
        float4 xa = xr[0];
        float4 xb = xr[1];

        float ca[NQ], sa[NQ];
        #pragma unroll
        for (int w = 0; w < NQ; ++w) {
            const float* wp = W_pre + w * INF;   // wave-uniform -> scalar loads
            float acc = b_pre[w];
            acc += xa.x * wp[0] + xa.y * wp[1] + xa.z * wp[2] + xa.w * wp[3];
            acc += xb.x * wp[4] + xb.y * wp[5] + xb.z * wp[6] + xb.w * wp[7];
            float alpha = 3.14159265358979323846f * fast_tanh(acc);
            __sincosf(0.5f * alpha, &sa[w], &ca[w]);
        }

        float ct[NL][NQ], st_[NL][NQ];
        #pragma unroll
        for (int l = 0; l < NL; ++l)
            #pragma unroll
            for (int w = 0; w < NQ; ++w)
                __sincosf(0.5f * theta[l * NQ + w], &st_[l][w], &ct[l][w]);

        // ---- phase 2: statevector sim (wire w <-> bit mask 8>>w) ----
        float st[16];
        #pragma unroll
        for (int i = 0; i < 16; ++i) {
            float v = (i & 8) ? sa[0] : ca[0];
            v *= (i & 4) ? sa[1] : ca[1];
            v *= (i & 2) ? sa[2] : ca[2];
            v *= (i & 1) ? sa[3] : ca[3];
            st[i] = v;
        }

        #pragma unroll
        for (int l = 0; l < NL; ++l) {
            #pragma unroll
            for (int w = 0; w < NQ; ++w) {
                const float c = ct[l][w], s = st_[l][w];
                const int bit = 8 >> w;
                #pragma unroll
                for (int i = 0; i < 16; ++i) {
                    if (!(i & bit)) {
                        const int j = i | bit;
                        float a0 = st[i], a1 = st[j];
                        st[i] = c * a0 - s * a1;
                        st[j] = s * a0 + c * a1;
                    }
                }
            }
            #pragma unroll
            for (int w = 0; w < NQ - 1; ++w) {
                const int cb = 8 >> w, tb = 8 >> (w + 1);
                #pragma unroll
                for (int i = 0; i < 16; ++i) {
                    if ((i & cb) && !(i & tb)) {
                        const int j = i | tb;
                        float t = st[i]; st[i] = st[j]; st[j] = t;
                    }
                }
            }
        }

        // ---- phase 3: PauliZ expectations ----
        float p[16];
        #pragma unroll
        for (int i = 0; i < 16; ++i) p[i] = st[i] * st[i];

        #pragma unroll
        for (int w = 0; w < NQ; ++w) {
            const int bit = 8 >> w;
            float zp = 0.f, zm = 0.f;
            #pragma unroll
            for (int i = 0; i < 16; ++i) {
                if (i & bit) zm += p[i]; else zp += p[i];
            }
            zsh[tid][w] = zp - zm;
        }
    }
    __syncthreads();

    // ---- phase 4: block-contiguous interleaved epilogue ----
    // Iteration i: wave wv writes rows {8i+2wv, 8i+2wv+1} of the block's 256.
    // The 4 waves together emit one contiguous 4KB line per iteration; the
    // block sweeps ONE contiguous 128KB stream (1024 streams device-wide,
    // vs 4096 per-wave streams before).
    const int lane  = tid & 63;
    const int wv    = tid >> 6;
    const int colb  = (lane & 31) * 4;   // column block [colb, colb+3]
    const int rhalf = lane >> 5;         // which of the 2 rows in the pair

    const float4 w0 = *reinterpret_cast<const float4*>(W_post + (colb + 0) * NQ);
    const float4 w1 = *reinterpret_cast<const float4*>(W_post + (colb + 1) * NQ);
    const float4 w2 = *reinterpret_cast<const float4*>(W_post + (colb + 2) * NQ);
    const float4 w3 = *reinterpret_cast<const float4*>(W_post + (colb + 3) * NQ);
    const float4 bp = *reinterpret_cast<const float4*>(b_post + colb);

    const int rinb0 = 2 * wv + rhalf;               // 0..7, row-in-block base
    const int rbase = blockIdx.x * 256 + rinb0;

    if (blockIdx.x * 256 + 255 < B) {
        // full block: no per-iter guard
        fv4* optr = reinterpret_cast<fv4*>(out + (size_t)rbase * OUTF + colb);
        #pragma unroll 8
        for (int i = 0; i < 32; ++i) {
            const int lr = 8 * i + rinb0;
            const float4 z = *reinterpret_cast<const float4*>(&zsh[lr][0]);
            fv4 o;
            o.x = fmaf(z.w, w0.w, fmaf(z.z, w0.z, fmaf(z.y, w0.y, fmaf(z.x, w0.x, bp.x))));
            o.y = fmaf(z.w, w1.w, fmaf(z.z, w1.z, fmaf(z.y, w1.y, fmaf(z.x, w1.x, bp.y))));
            o.z = fmaf(z.w, w2.w, fmaf(z.z, w2.z, fmaf(z.y, w2.y, fmaf(z.x, w2.x, bp.z))));
            o.w = fmaf(z.w, w3.w, fmaf(z.z, w3.z, fmaf(z.y, w3.y, fmaf(z.x, w3.x, bp.w))));
            __builtin_nontemporal_store(o, optr + (size_t)8 * i * (OUTF / 4));
        }
    } else {
        for (int i = 0; i < 32; ++i) {
            const int rr = rbase + 8 * i;
            if (rr >= B) break;
            const int lr = 8 * i + rinb0;
            const float4 z = *reinterpret_cast<const float4*>(&zsh[lr][0]);
            float4 o;
            o.x = fmaf(z.w, w0.w, fmaf(z.z, w0.z, fmaf(z.y, w0.y, fmaf(z.x, w0.x, bp.x))));
            o.y = fmaf(z.w, w1.w, fmaf(z.z, w1.z, fmaf(z.y, w1.y, fmaf(z.x, w1.x, bp.y))));
            o.z = fmaf(z.w, w2.w, fmaf(z.z, w2.z, fmaf(z.y, w2.y, fmaf(z.x, w2.x, bp.z))));
            o.w = fmaf(z.w, w3.w, fmaf(z.z, w3.z, fmaf(z.y, w3.y, fmaf(z.x, w3.x, bp.w))));
            *reinterpret_cast<float4*>(out + (size_t)rr * OUTF + colb) = o;
        }
    }
}

extern "C" void kernel_launch(void* const* d_in, const int* in_sizes, int n_in,
                              void* d_out, int out_size, void* d_ws, size_t ws_size,
                              hipStream_t stream) {
    const float* x      = (const float*)d_in[0];
    const float* W_pre  = (const float*)d_in[1];
    const float* b_pre  = (const float*)d_in[2];
    const float* theta  = (const float*)d_in[3];
    const float* W_post = (const float*)d_in[4];
    const float* b_post = (const float*)d_in[5];
    float* out = (float*)d_out;

    const int B = in_sizes[0] / INF;
    const int nblocks = (B + 255) / 256;
    tq_kernel<<<dim3(nblocks), dim3(256), 0, stream>>>(
        x, W_pre, b_pre, theta, W_post, b_post, out, B);
}

// Round 7
// 27.103 us; speedup vs baseline: 1.6173x; 1.1371x over previous
//
#include <hip/hip_runtime.h>
#include <math.h>

#define NQ 4
#define NL 2
#define INF 8
#define OUTF 128

typedef float fv4 __attribute__((ext_vector_type(4)));

__device__ __forceinline__ float fast_tanh(float x) {
    float e = __expf(2.0f * x);
    return 1.0f - 2.0f / (e + 1.0f);
}

__global__ __launch_bounds__(256) void tq_kernel(
    const float* __restrict__ x,       // [B,8]
    const float* __restrict__ W_pre,   // [4,8]
    const float* __restrict__ b_pre,   // [4]
    const float* __restrict__ theta,   // [2,4]
    const float* __restrict__ W_post,  // [128,4]
    const float* __restrict__ b_post,  // [128]
    float* __restrict__ out,           // [B,128]
    int B)
{
    const int tid = threadIdx.x;
    const int row = blockIdx.x * 256 + tid;

    __shared__ float zsh[256][4];

    if (row < B) {
        // ---- phase 1: embedding angles ----
        const float4* xr = reinterpret_cast<const float4*>(x + (size_t)row * INF);
        float4 xa = xr[0];
        float4 xb = xr[1];

        float ca[NQ], sa[NQ];
        #pragma unroll
        for (int w = 0; w < NQ; ++w) {
            const float* wp = W_pre + w * INF;   // wave-uniform -> scalar loads
            float acc = b_pre[w];
            acc += xa.x * wp[0] + xa.y * wp[1] + xa.z * wp[2] + xa.w * wp[3];
            acc += xb.x * wp[4] + xb.y * wp[5] + xb.z * wp[6] + xb.w * wp[7];
            float alpha = 3.14159265358979323846f * fast_tanh(acc);
            __sincosf(0.5f * alpha, &sa[w], &ca[w]);
        }

        float ct[NL][NQ], st_[NL][NQ];
        #pragma unroll
        for (int l = 0; l < NL; ++l)
            #pragma unroll
            for (int w = 0; w < NQ; ++w)
                __sincosf(0.5f * theta[l * NQ + w], &st_[l][w], &ct[l][w]);

        // ---- phase 2: statevector sim (wire w <-> bit mask 8>>w) ----
        float st[16];
        #pragma unroll
        for (int i = 0; i < 16; ++i) {
            float v = (i & 8) ? sa[0] : ca[0];
            v *= (i & 4) ? sa[1] : ca[1];
            v *= (i & 2) ? sa[2] : ca[2];
            v *= (i & 1) ? sa[3] : ca[3];
            st[i] = v;
        }

        #pragma unroll
        for (int l = 0; l < NL; ++l) {
            #pragma unroll
            for (int w = 0; w < NQ; ++w) {
                const float c = ct[l][w], s = st_[l][w];
                const int bit = 8 >> w;
                #pragma unroll
                for (int i = 0; i < 16; ++i) {
                    if (!(i & bit)) {
                        const int j = i | bit;
                        float a0 = st[i], a1 = st[j];
                        st[i] = c * a0 - s * a1;
                        st[j] = s * a0 + c * a1;
                    }
                }
            }
            #pragma unroll
            for (int w = 0; w < NQ - 1; ++w) {
                const int cb = 8 >> w, tb = 8 >> (w + 1);
                #pragma unroll
                for (int i = 0; i < 16; ++i) {
                    if ((i & cb) && !(i & tb)) {
                        const int j = i | tb;
                        float t = st[i]; st[i] = st[j]; st[j] = t;
                    }
                }
            }
        }

        // ---- phase 3: PauliZ expectations ----
        float p[16];
        #pragma unroll
        for (int i = 0; i < 16; ++i) p[i] = st[i] * st[i];

        #pragma unroll
        for (int w = 0; w < NQ; ++w) {
            const int bit = 8 >> w;
            float zp = 0.f, zm = 0.f;
            #pragma unroll
            for (int i = 0; i < 16; ++i) {
                if (i & bit) zm += p[i]; else zp += p[i];
            }
            zsh[tid][w] = zp - zm;
        }
    }
    __syncthreads();

    // ---- phase 4: coalesced float4 epilogue (PLAIN stores — A/B vs R3's nt)
    const int lane  = tid & 63;
    const int wv    = tid >> 6;
    const int colb  = (lane & 31) * 4;   // column block [colb, colb+3]
    const int rhalf = lane >> 5;         // 0 or 1: which of the 2 rows/iter

    const float4 w0 = *reinterpret_cast<const float4*>(W_post + (colb + 0) * NQ);
    const float4 w1 = *reinterpret_cast<const float4*>(W_post + (colb + 1) * NQ);
    const float4 w2 = *reinterpret_cast<const float4*>(W_post + (colb + 2) * NQ);
    const float4 w3 = *reinterpret_cast<const float4*>(W_post + (colb + 3) * NQ);
    const float4 bp = *reinterpret_cast<const float4*>(b_post + colb);

    const int lr0   = wv * 64 + rhalf;
    const int rbase = blockIdx.x * 256 + wv * 64 + rhalf;

    if (rbase + 62 < B) {
        fv4* optr = reinterpret_cast<fv4*>(out + (size_t)rbase * OUTF + colb);
        #pragma unroll 8
        for (int r = 0; r < 32; ++r) {
            const int lr = lr0 + 2 * r;
            const float4 z = *reinterpret_cast<const float4*>(&zsh[lr][0]);
            fv4 o;
            o.x = fmaf(z.w, w0.w, fmaf(z.z, w0.z, fmaf(z.y, w0.y, fmaf(z.x, w0.x, bp.x))));
            o.y = fmaf(z.w, w1.w, fmaf(z.z, w1.z, fmaf(z.y, w1.y, fmaf(z.x, w1.x, bp.y))));
            o.z = fmaf(z.w, w2.w, fmaf(z.z, w2.z, fmaf(z.y, w2.y, fmaf(z.x, w2.x, bp.z))));
            o.w = fmaf(z.w, w3.w, fmaf(z.z, w3.z, fmaf(z.y, w3.y, fmaf(z.x, w3.x, bp.w))));
            optr[(size_t)2 * r * (OUTF / 4)] = o;   // plain writeback store
        }
    } else {
        for (int r = 0; r < 32; ++r) {
            const int rr = rbase + 2 * r;
            if (rr >= B) break;
            const int lr = lr0 + 2 * r;
            const float4 z = *reinterpret_cast<const float4*>(&zsh[lr][0]);
            float4 o;
            o.x = fmaf(z.w, w0.w, fmaf(z.z, w0.z, fmaf(z.y, w0.y, fmaf(z.x, w0.x, bp.x))));
            o.y = fmaf(z.w, w1.w, fmaf(z.z, w1.z, fmaf(z.y, w1.y, fmaf(z.x, w1.x, bp.y))));
            o.z = fmaf(z.w, w2.w, fmaf(z.z, w2.z, fmaf(z.y, w2.y, fmaf(z.x, w2.x, bp.z))));
            o.w = fmaf(z.w, w3.w, fmaf(z.z, w3.z, fmaf(z.y, w3.y, fmaf(z.x, w3.x, bp.w))));
            *reinterpret_cast<float4*>(out + (size_t)rr * OUTF + colb) = o;
        }
    }
}

extern "C" void kernel_launch(void* const* d_in, const int* in_sizes, int n_in,
                              void* d_out, int out_size, void* d_ws, size_t ws_size,
                              hipStream_t stream) {
    const float* x      = (const float*)d_in[0];
    const float* W_pre  = (const float*)d_in[1];
    const float* b_pre  = (const float*)d_in[2];
    const float* theta  = (const float*)d_in[3];
    const float* W_post = (const float*)d_in[4];
    const float* b_post = (const float*)d_in[5];
    float* out = (float*)d_out;

    const int B = in_sizes[0] / INF;
    const int nblocks = (B + 255) / 256;
    tq_kernel<<<dim3(nblocks), dim3(256), 0, stream>>>(
        x, W_pre, b_pre, theta, W_post, b_post, out, B);
}

// Round 8
// 26.936 us; speedup vs baseline: 1.6273x; 1.0062x over previous
//
#include <hip/hip_runtime.h>
#include <math.h>

#define NQ 4
#define NL 2
#define INF 8
#define OUTF 128
#define ROWS_PER_WAVE 128   // 2 chunks of 64
#define ROWS_PER_BLOCK 512  // 4 waves * 128

typedef float fv4 __attribute__((ext_vector_type(4)));

__device__ __forceinline__ float fast_tanh(float x) {
    float e = __expf(2.0f * x);
    return 1.0f - 2.0f / (e + 1.0f);
}

__device__ __forceinline__ void circuit(
    const float4& xa, const float4& xb,
    const float* __restrict__ W_pre, const float* __restrict__ b_pre,
    const float ct[NL][NQ], const float st_[NL][NQ], float z[NQ])
{
    float ca[NQ], sa[NQ];
    #pragma unroll
    for (int w = 0; w < NQ; ++w) {
        const float* wp = W_pre + w * INF;   // wave-uniform -> scalar loads
        float acc = b_pre[w];
        acc += xa.x * wp[0] + xa.y * wp[1] + xa.z * wp[2] + xa.w * wp[3];
        acc += xb.x * wp[4] + xb.y * wp[5] + xb.z * wp[6] + xb.w * wp[7];
        float alpha = 3.14159265358979323846f * fast_tanh(acc);
        __sincosf(0.5f * alpha, &sa[w], &ca[w]);
    }

    float st[16];
    #pragma unroll
    for (int i = 0; i < 16; ++i) {
        float v = (i & 8) ? sa[0] : ca[0];
        v *= (i & 4) ? sa[1] : ca[1];
        v *= (i & 2) ? sa[2] : ca[2];
        v *= (i & 1) ? sa[3] : ca[3];
        st[i] = v;
    }

    #pragma unroll
    for (int l = 0; l < NL; ++l) {
        #pragma unroll
        for (int w = 0; w < NQ; ++w) {
            const float c = ct[l][w], s = st_[l][w];
            const int bit = 8 >> w;
            #pragma unroll
            for (int i = 0; i < 16; ++i) {
                if (!(i & bit)) {
                    const int j = i | bit;
                    float a0 = st[i], a1 = st[j];
                    st[i] = c * a0 - s * a1;
                    st[j] = s * a0 + c * a1;
                }
            }
        }
        #pragma unroll
        for (int w = 0; w < NQ - 1; ++w) {
            const int cb = 8 >> w, tb = 8 >> (w + 1);
            #pragma unroll
            for (int i = 0; i < 16; ++i) {
                if ((i & cb) && !(i & tb)) {
                    const int j = i | tb;
                    float t = st[i]; st[i] = st[j]; st[j] = t;
                }
            }
        }
    }

    float p[16];
    #pragma unroll
    for (int i = 0; i < 16; ++i) p[i] = st[i] * st[i];

    #pragma unroll
    for (int w = 0; w < NQ; ++w) {
        const int bit = 8 >> w;
        float zp = 0.f, zm = 0.f;
        #pragma unroll
        for (int i = 0; i < 16; ++i) {
            if (i & bit) zm += p[i]; else zp += p[i];
        }
        z[w] = zp - zm;
    }
}

__global__ __launch_bounds__(256) void tq_kernel(
    const float* __restrict__ x,       // [B,8]
    const float* __restrict__ W_pre,   // [4,8]
    const float* __restrict__ b_pre,   // [4]
    const float* __restrict__ theta,   // [2,4]
    const float* __restrict__ W_post,  // [128,4]
    const float* __restrict__ b_post,  // [128]
    float* __restrict__ out,           // [B,128]
    int B)
{
    const int tid  = threadIdx.x;
    const int lane = tid & 63;
    const int wv   = tid >> 6;

    __shared__ float zbuf[4][64][4];   // per-wave private 1KB region

    float ct[NL][NQ], st_[NL][NQ];
    #pragma unroll
    for (int l = 0; l < NL; ++l)
        #pragma unroll
        for (int w = 0; w < NQ; ++w)
            __sincosf(0.5f * theta[l * NQ + w], &st_[l][w], &ct[l][w]);

    const int colb  = (lane & 31) * 4;
    const int rhalf = lane >> 5;
    const float4 w0 = *reinterpret_cast<const float4*>(W_post + (colb + 0) * NQ);
    const float4 w1 = *reinterpret_cast<const float4*>(W_post + (colb + 1) * NQ);
    const float4 w2 = *reinterpret_cast<const float4*>(W_post + (colb + 2) * NQ);
    const float4 w3 = *reinterpret_cast<const float4*>(W_post + (colb + 3) * NQ);
    const float4 bp = *reinterpret_cast<const float4*>(b_post + colb);

    const int wbase = blockIdx.x * ROWS_PER_BLOCK + wv * ROWS_PER_WAVE;

    if (wbase + ROWS_PER_WAVE <= B) {
        // ---------------- fast path: full 128-row wave, no guards --------
        const float4* xr0 = reinterpret_cast<const float4*>(x + (size_t)(wbase + lane) * INF);
        float4 xa0 = xr0[0], xb0 = xr0[1];
        float z0[NQ];
        circuit(xa0, xb0, W_pre, b_pre, ct, st_, z0);
        *reinterpret_cast<float4*>(&zbuf[wv][lane][0]) = make_float4(z0[0], z0[1], z0[2], z0[3]);

        // prefetch chunk-1 x BEFORE stores: vmcnt wait for x1 then doesn't
        // drain the store queue (in-order vmcnt, loads issued first)
        const float4* xr1 = reinterpret_cast<const float4*>(x + (size_t)(wbase + 64 + lane) * INF);
        float4 xa1 = xr1[0], xb1 = xr1[1];

        asm volatile("s_waitcnt lgkmcnt(0)" ::: "memory");

        // chunk 0 stores (plain writeback)
        {
            const int rbase = wbase + rhalf;
            fv4* optr = reinterpret_cast<fv4*>(out + (size_t)rbase * OUTF + colb);
            #pragma unroll 8
            for (int r = 0; r < 32; ++r) {
                const int lr = rhalf + 2 * r;
                const float4 z = *reinterpret_cast<const float4*>(&zbuf[wv][lr][0]);
                fv4 o;
                o.x = fmaf(z.w, w0.w, fmaf(z.z, w0.z, fmaf(z.y, w0.y, fmaf(z.x, w0.x, bp.x))));
                o.y = fmaf(z.w, w1.w, fmaf(z.z, w1.z, fmaf(z.y, w1.y, fmaf(z.x, w1.x, bp.y))));
                o.z = fmaf(z.w, w2.w, fmaf(z.z, w2.z, fmaf(z.y, w2.y, fmaf(z.x, w2.x, bp.z))));
                o.w = fmaf(z.w, w3.w, fmaf(z.z, w3.z, fmaf(z.y, w3.y, fmaf(z.x, w3.x, bp.w))));
                optr[(size_t)2 * r * (OUTF / 4)] = o;
            }
        }

        // chunk 1 circuit overlaps chunk-0 store drain
        float z1[NQ];
        circuit(xa1, xb1, W_pre, b_pre, ct, st_, z1);
        *reinterpret_cast<float4*>(&zbuf[wv][lane][0]) = make_float4(z1[0], z1[1], z1[2], z1[3]);
        asm volatile("s_waitcnt lgkmcnt(0)" ::: "memory");

        // chunk 1 stores
        {
            const int rbase = wbase + 64 + rhalf;
            fv4* optr = reinterpret_cast<fv4*>(out + (size_t)rbase * OUTF + colb);
            #pragma unroll 8
            for (int r = 0; r < 32; ++r) {
                const int lr = rhalf + 2 * r;
                const float4 z = *reinterpret_cast<const float4*>(&zbuf[wv][lr][0]);
                fv4 o;
                o.x = fmaf(z.w, w0.w, fmaf(z.z, w0.z, fmaf(z.y, w0.y, fmaf(z.x, w0.x, bp.x))));
                o.y = fmaf(z.w, w1.w, fmaf(z.z, w1.z, fmaf(z.y, w1.y, fmaf(z.x, w1.x, bp.y))));
                o.z = fmaf(z.w, w2.w, fmaf(z.z, w2.z, fmaf(z.y, w2.y, fmaf(z.x, w2.x, bp.z))));
                o.w = fmaf(z.w, w3.w, fmaf(z.z, w3.z, fmaf(z.y, w3.y, fmaf(z.x, w3.x, bp.w))));
                optr[(size_t)2 * r * (OUTF / 4)] = o;
            }
        }
    } else {
        // ---------------- guarded tail path ------------------------------
        for (int c = 0; c < 2; ++c) {
            const int cbase = wbase + 64 * c;
            if (cbase >= B) break;
            const int myrow = cbase + lane;
            if (myrow < B) {
                const float4* xr = reinterpret_cast<const float4*>(x + (size_t)myrow * INF);
                float4 xa = xr[0], xb = xr[1];
                float z[NQ];
                circuit(xa, xb, W_pre, b_pre, ct, st_, z);
                *reinterpret_cast<float4*>(&zbuf[wv][lane][0]) = make_float4(z[0], z[1], z[2], z[3]);
            }
            asm volatile("s_waitcnt lgkmcnt(0)" ::: "memory");
            for (int r = 0; r < 32; ++r) {
                const int rr = cbase + rhalf + 2 * r;
                if (rr >= B) break;
                const int lr = rhalf + 2 * r;
                const float4 z = *reinterpret_cast<const float4*>(&zbuf[wv][lr][0]);
                float4 o;
                o.x = fmaf(z.w, w0.w, fmaf(z.z, w0.z, fmaf(z.y, w0.y, fmaf(z.x, w0.x, bp.x))));
                o.y = fmaf(z.w, w1.w, fmaf(z.z, w1.z, fmaf(z.y, w1.y, fmaf(z.x, w1.x, bp.y))));
                o.z = fmaf(z.w, w2.w, fmaf(z.z, w2.z, fmaf(z.y, w2.y, fmaf(z.x, w2.x, bp.z))));
                o.w = fmaf(z.w, w3.w, fmaf(z.z, w3.z, fmaf(z.y, w3.y, fmaf(z.x, w3.x, bp.w))));
                *reinterpret_cast<float4*>(out + (size_t)rr * OUTF + colb) = o;
            }
            asm volatile("s_waitcnt lgkmcnt(0)" ::: "memory");
        }
    }
}

extern "C" void kernel_launch(void* const* d_in, const int* in_sizes, int n_in,
                              void* d_out, int out_size, void* d_ws, size_t ws_size,
                              hipStream_t stream) {
    const float* x      = (const float*)d_in[0];
    const float* W_pre  = (const float*)d_in[1];
    const float* b_pre  = (const float*)d_in[2];
    const float* theta  = (const float*)d_in[3];
    const float* W_post = (const float*)d_in[4];
    const float* b_post = (const float*)d_in[5];
    float* out = (float*)d_out;

    const int B = in_sizes[0] / INF;
    const int nblocks = (B + ROWS_PER_BLOCK - 1) / ROWS_PER_BLOCK;
    tq_kernel<<<dim3(nblocks), dim3(256), 0, stream>>>(
        x, W_pre, b_pre, theta, W_post, b_post, out, B);
}